// Round 14
// baseline (260.643 us; speedup 1.0000x reference)
//
#include <hip/hip_runtime.h>
#include <math.h>

typedef __attribute__((ext_vector_type(8))) short short8;
typedef __attribute__((ext_vector_type(4))) float f32x4;
typedef __attribute__((ext_vector_type(2))) float f32x2;
typedef _Float16 f16x8 __attribute__((ext_vector_type(8)));

#define TILE 16
#define IH 256
#define IW 256

// ws byte layout: [0,16384) kc f32[64][64]; [16384,81920) wsA frags ushort (bf16);
//                 [81920,114688) wsC frags ushort (f16)
#define WSA_OFF 16384
#define WSC_OFF 81920

// LDS layout (bytes):
//   H[2]: double-buffered, each [16 ch][1456] (18 rows x 80B + 16B pad); px = packed f16 (h1,h2)
//   G[2]: @46592, each [256 px][64B = 4 granules, XOR gi=(ch>>3)^((px>>4)&3)], f16
//   slow-path YS f32[32][260] (33280 B) overlays @0
#define H_STRIDE 1456
#define H_BUF 23296
#define G_OFF 46592
#define G_BUF 16384
#define SMEM_BYTES 79360

__device__ __forceinline__ unsigned short f2bf(float f) {
  unsigned int u = __builtin_bit_cast(unsigned int, f);
  u = (u + 0x7FFFu + ((u >> 16) & 1u)) >> 16;
  return (unsigned short)u;
}

__global__ void edffn_prep(const float* __restrict__ fftf,
                           const float* __restrict__ w_in,
                           const float* __restrict__ w_out,
                           float* __restrict__ ws) {
  int blk = blockIdx.x, t = threadIdx.x;
  if (blk < 64) {
    // kc = irfft2 of the (real, symmetric) full-spectrum multiplier
    int a = t >> 3, bb = t & 7;
    const float c0 = 0.70710678118654752f;
    const float ctab[8] = {1.f, c0, 0.f, -c0, -1.f, -c0, 0.f, c0};
    const float* F = fftf + blk * 40;  // [8][5]
    float acc = 0.f;
    for (int k1 = 0; k1 < 8; ++k1)
      for (int k2 = 0; k2 < 8; ++k2) {
        float f = (k2 <= 4) ? F[k1 * 5 + k2] : F[((8 - k1) & 7) * 5 + (8 - k2)];
        acc += f * ctab[(k1 * a + k2 * bb) & 7];
      }
    ws[blk * 64 + t] = acc * (1.f / 64.f);
  } else if (blk < 128) {
    // w_in A-fragments (bf16): [chunk q=0..15][s=0,1][ks=0,1][lane][8]
    int b2 = blk - 64;
    int q = b2 >> 2, s = (b2 >> 1) & 1, ks = b2 & 1;
    int row = (s ? 256 : 0) + q * 16 + (t & 15);
    unsigned short* dst =
        (unsigned short*)((unsigned char*)ws + WSA_OFF) + (((q * 2 + s) * 2 + ks) * 64 + t) * 8;
    for (int j = 0; j < 8; ++j) {
      int k = ks * 32 + (t >> 4) * 8 + j;
      dst[j] = f2bf(w_in[row * 64 + k]);
    }
  } else {
    // w_out A-fragments (f16): [pair p=0..7][mtile=0..3][lane][8]
    int b3 = blk - 128;
    int p = b3 >> 2, mt = b3 & 3;
    int row = mt * 16 + (t & 15);
    unsigned short* dst =
        (unsigned short*)((unsigned char*)ws + WSC_OFF) + ((p * 4 + mt) * 64 + t) * 8;
    for (int j = 0; j < 8; ++j) {
      int k = p * 32 + (t >> 4) * 8 + j;
      _Float16 hv = (_Float16)w_out[row * 256 + k];
      dst[j] = __builtin_bit_cast(unsigned short, hv);
    }
  }
}

__global__ __launch_bounds__(256, 2) void edffn_main(
    const float* __restrict__ x, const float* __restrict__ b_in,
    const float* __restrict__ w_dw, const float* __restrict__ b_dw,
    const float* __restrict__ b_out, const float* __restrict__ ws,
    float* __restrict__ out) {
  __shared__ __align__(16) unsigned char smem[SMEM_BYTES];
  __shared__ int s_flag;
  const int t = threadIdx.x;
  const int lane = t & 63, wave = t >> 6;
  const int l15 = lane & 15, lg = lane >> 4;
  const int gx0 = blockIdx.x * TILE, gy0 = blockIdx.y * TILE;
  const int b = blockIdx.z;
  const unsigned short* wsA = (const unsigned short*)((const unsigned char*)ws + WSA_OFF);
  const unsigned short* wsC = (const unsigned short*)((const unsigned char*)ws + WSC_OFF);

  // ---- stage-A B-fragments (x halo, bf16) held in registers across all chunks ----
  short8 xf[6][2];
  int haddr[6];
  unsigned vmask = 0, imask = 0;
  const float* xb = x + (size_t)b * 64 * 65536;
#pragma unroll
  for (int i = 0; i < 6; ++i) {
    int nt = wave + 4 * i;  // wave0: 0,4,..,20 ; waves1-3: last invalid
    int n = nt * 16 + l15;
    int hy = n / 18;
    int hx = n - hy * 18;
    int gy = gy0 + hy - 1, gx = gx0 + hx - 1;
    int vnt = (nt < 21) & (n < 324);
    int inb = vnt & (gy >= 0) & (gy < IH) & (gx >= 0) & (gx < IW);
    haddr[i] = hy * 80 + hx * 4;
    vmask |= (unsigned)vnt << i;
    imask |= (unsigned)inb << i;
    int gyc = min(max(gy, 0), IH - 1), gxc = min(max(gx, 0), IW - 1);
    const float* xp = xb + (size_t)gyc * IW + gxc;
#pragma unroll
    for (int ks = 0; ks < 2; ++ks) {
#pragma unroll
      for (int j = 0; j < 8; ++j) {
        int k = ks * 32 + lg * 8 + j;
        unsigned short bf = f2bf(xp[(size_t)k * 65536]);
        xf[i][ks][j] = (short)(inb ? bf : (unsigned short)0);
      }
    }
  }

  f32x4 accY[16];
#pragma unroll
  for (int i = 0; i < 16; ++i) accY[i] = (f32x4){0.f, 0.f, 0.f, 0.f};

  const int cp_dw = t & 15;  // channel-in-chunk (wave spans all 16)
  const int oy_dw = t >> 4;  // output row 0..15

  auto loadWD = [&](int qq, unsigned (&wd)[9], unsigned& bd) {
    const int cg1 = qq * 16 + cp_dw, cg2 = 256 + qq * 16 + cp_dw;
#pragma unroll
    for (int u = 0; u < 9; ++u) {
      float w1 = w_dw[cg1 * 9 + u], w2 = w_dw[cg2 * 9 + u];
      asm("v_cvt_pkrtz_f16_f32 %0, %1, %2" : "=v"(wd[u]) : "v"(w1), "v"(w2));
    }
    float b1 = b_dw[cg1], b2 = b_dw[cg2];
    asm("v_cvt_pkrtz_f16_f32 %0, %1, %2" : "=v"(bd) : "v"(b1), "v"(b2));
  };

  // stage A for chunk qq into H[qq&1]
  auto stageA = [&](int qq) {
    short8 af[2][2];
#pragma unroll
    for (int s = 0; s < 2; ++s)
#pragma unroll
      for (int ks = 0; ks < 2; ++ks)
        af[s][ks] = *(const short8*)(wsA + (((qq * 2 + s) * 2 + ks) * 64 + lane) * 8);
    float bin[2][4];
#pragma unroll
    for (int s = 0; s < 2; ++s)
#pragma unroll
      for (int r = 0; r < 4; ++r) bin[s][r] = b_in[(s ? 256 : 0) + qq * 16 + lg * 4 + r];
    unsigned char* Hb = smem + (qq & 1) * H_BUF;
#pragma unroll
    for (int i = 0; i < 6; ++i) {
      if (wave + 4 * i < 21) {  // wave-uniform
        f32x4 acc0 = {0.f, 0.f, 0.f, 0.f}, acc1 = {0.f, 0.f, 0.f, 0.f};
        acc0 = __builtin_amdgcn_mfma_f32_16x16x32_bf16(af[0][0], xf[i][0], acc0, 0, 0, 0);
        acc0 = __builtin_amdgcn_mfma_f32_16x16x32_bf16(af[0][1], xf[i][1], acc0, 0, 0, 0);
        acc1 = __builtin_amdgcn_mfma_f32_16x16x32_bf16(af[1][0], xf[i][0], acc1, 0, 0, 0);
        acc1 = __builtin_amdgcn_mfma_f32_16x16x32_bf16(af[1][1], xf[i][1], acc1, 0, 0, 0);
        if ((vmask >> i) & 1u) {  // per-lane mask on writes only (MFMA stays convergent)
          unsigned keep = (imask >> i) & 1u;
#pragma unroll
          for (int r = 0; r < 4; ++r) {
            float v0 = acc0[r] + bin[0][r];
            float v1 = acc1[r] + bin[1][r];
            unsigned pk;
            asm("v_cvt_pkrtz_f16_f32 %0, %1, %2" : "=v"(pk) : "v"(v0), "v"(v1));
            pk = keep ? pk : 0u;  // SAME pad: h=0 outside image
            *(unsigned*)(Hb + (lg * 4 + r) * H_STRIDE + haddr[i]) = pk;
          }
        }
      }
    }
  };

  // packed-f16 GELU constants
#define PKC(nm, val)                                            \
  unsigned nm;                                                  \
  {                                                             \
    float fv = (val);                                           \
    asm("v_cvt_pkrtz_f16_f32 %0, %1, %1" : "=v"(nm) : "v"(fv)); \
  }
  PKC(kSQ, 0.70710678f)
  PKC(kC216, 1.f / 216.f)
  PKC(kCm42, -1.f / 42.f)
  PKC(kC10, 0.1f)
  PKC(kCm3, -1.f / 3.f)
  PKC(kOne, 1.0f)
  PKC(kHalf, 0.5f)
  PKC(kErf, 1.12837917f)
#undef PKC

  unsigned wdC[9], wdN[9], bdC, bdN;
  f16x8 cfC;
  loadWD(0, wdC, bdC);
  cfC = *(const f16x8*)(wsC + ((0 * 4 + wave) * 64 + lane) * 8);

  // ---- prologue: H(0) ----
  stageA(0);
  __syncthreads();

  for (int q = 0; q < 16; ++q) {
    // ---- stage C (split): handle h=q-2 -> pair p=h>>1, 8 nt, from G[p&1] ----
    if (q >= 2) {
      const int h = q - 2;
      const int p = h >> 1;
      const int nt0 = (h & 1) * 8;
      const unsigned short* G =
          (const unsigned short*)(smem + G_OFF + (p & 1) * G_BUF);
#pragma unroll
      for (int k = 0; k < 8; ++k) {
        int nt = nt0 + k;
        int g = lg ^ (nt & 3);  // reader-side XOR (nt uniform per instr)
        int n = nt * 16 + l15;
        f16x8 bf = *(const f16x8*)(G + n * 32 + g * 8);
        accY[nt] = __builtin_amdgcn_mfma_f32_16x16x32_f16(cfC, bf, accY[nt], 0, 0, 0);
      }
      if (h & 1)  // finished a pair: prefetch next pair's w_out fragment
        cfC = *(const f16x8*)(wsC + (((p + 1) * 4 + wave) * 64 + lane) * 8);
    }

    if (q < 15) loadWD(q + 1, wdN, bdN);

    // ---- dwconv 3x3 + GELU gate, packed f16; reads H[q&1], writes G[(q>>1)&1] ----
    {
      const int cp = cp_dw, oy = oy_dw;
      const unsigned char* Hb = smem + (q & 1) * H_BUF;
      unsigned a[16];
#pragma unroll
      for (int j = 0; j < 16; ++j) a[j] = bdC;
#pragma unroll
      for (int dy = 0; dy < 3; ++dy) {
        const uint4* rp = (const uint4*)(Hb + cp * H_STRIDE + (oy + dy) * 80);
        uint4 r0 = rp[0], r1 = rp[1], r2 = rp[2], r3 = rp[3];
        uint2 r4 = ((const uint2*)rp)[8];
        unsigned e[18] = {r0.x, r0.y, r0.z, r0.w, r1.x, r1.y, r1.z, r1.w,
                          r2.x, r2.y, r2.z, r2.w, r3.x, r3.y, r3.z, r3.w,
                          r4.x, r4.y};
#pragma unroll
        for (int ox = 0; ox < 16; ++ox) {
#pragma unroll
          for (int dx = 0; dx < 3; ++dx)
            asm("v_pk_fma_f16 %0, %1, %2, %0"
                : "+v"(a[ox])
                : "v"(wdC[dy * 3 + dx]), "v"(e[ox + dx]));
        }
      }
      const int c2 = (q & 1) * 16 + cp;
      const int gi = (c2 >> 3) ^ (oy & 3);  // 16B-granule XOR swizzle (involution)
      unsigned short* Gp = (unsigned short*)(smem + G_OFF + ((q >> 1) & 1) * G_BUF) +
                           oy * 16 * 32 + gi * 8 + (c2 & 7);
      // packed-f16 GELU: u = (h1,h1') lows, v = (h2,h2') highs per ox pair
      unsigned umax = 0;
      unsigned gw[8];
#pragma unroll
      for (int j = 0; j < 8; ++j) {
        unsigned a0 = a[2 * j], a1 = a[2 * j + 1];
        unsigned u = __builtin_amdgcn_perm(a1, a0, 0x05040100u);
        unsigned v = __builtin_amdgcn_perm(a1, a0, 0x07060302u);
        unsigned uabs = u & 0x7FFF7FFFu;
        asm("v_pk_max_f16 %0, %1, %2" : "=v"(umax) : "v"(umax), "v"(uabs));
        unsigned z, z2, p, erfv, tt, g;
        asm("v_pk_mul_f16 %0, %1, %2" : "=v"(z) : "v"(u), "v"(kSQ));
        asm("v_pk_mul_f16 %0, %1, %2" : "=v"(z2) : "v"(z), "v"(z));
        asm("v_pk_fma_f16 %0, %1, %2, %3" : "=v"(p) : "v"(z2), "v"(kC216), "v"(kCm42));
        asm("v_pk_fma_f16 %0, %1, %2, %3" : "=v"(p) : "v"(z2), "v"(p), "v"(kC10));
        asm("v_pk_fma_f16 %0, %1, %2, %3" : "=v"(p) : "v"(z2), "v"(p), "v"(kCm3));
        asm("v_pk_fma_f16 %0, %1, %2, %3" : "=v"(p) : "v"(z2), "v"(p), "v"(kOne));
        asm("v_pk_mul_f16 %0, %1, %2" : "=v"(erfv) : "v"(z), "v"(p));
        asm("v_pk_mul_f16 %0, %1, %2" : "=v"(erfv) : "v"(erfv), "v"(kErf));
        asm("v_pk_fma_f16 %0, %1, %2, %2" : "=v"(tt) : "v"(erfv), "v"(kHalf));
        asm("v_pk_mul_f16 %0, %1, %2" : "=v"(g) : "v"(u), "v"(tt));
        asm("v_pk_mul_f16 %0, %1, %2" : "=v"(g) : "v"(g), "v"(v));
        gw[j] = g;
      }
      {  // exact fallback if any |z|>0.4 (cold; preserves correctness for any data)
        float m0, m1;
        unsigned uh = umax >> 16;
        asm("v_cvt_f32_f16 %0, %1" : "=v"(m0) : "v"(umax));
        asm("v_cvt_f32_f16 %0, %1" : "=v"(m1) : "v"(uh));
        if (__builtin_expect(fmaxf(m0, m1) > 0.565685f, 0)) {
#pragma unroll
          for (int j = 0; j < 8; ++j) {
            float g01[2];
#pragma unroll
            for (int kx = 0; kx < 2; ++kx) {
              unsigned aw = a[2 * j + kx], ah = aw >> 16;
              float hu, hv2;
              asm("v_cvt_f32_f16 %0, %1" : "=v"(hu) : "v"(aw));
              asm("v_cvt_f32_f16 %0, %1" : "=v"(hv2) : "v"(ah));
              g01[kx] = 0.5f * hu * (1.f + erff(hu * 0.70710678f)) * hv2;
            }
            unsigned pk;
            asm("v_cvt_pkrtz_f16_f32 %0, %1, %2" : "=v"(pk) : "v"(g01[0]), "v"(g01[1]));
            gw[j] = pk;
          }
        }
      }
#pragma unroll
      for (int j = 0; j < 8; ++j) {
        Gp[(2 * j) * 32] = (unsigned short)gw[j];
        Gp[(2 * j + 1) * 32] = (unsigned short)(gw[j] >> 16);
      }
    }

    // ---- stage A for chunk q+1 into H[(q+1)&1] (same region; scheduler overlaps) ----
    if (q < 15) stageA(q + 1);

    // rotate dwconv weights
    if (q < 15) {
#pragma unroll
      for (int u = 0; u < 9; ++u) wdC[u] = wdN[u];
      bdC = bdN;
    }
    __syncthreads();  // single barrier per chunk
  }

  // ---- final stage C: handles 14,15 = pair 7 from G[1] ----
  {
    const unsigned short* G = (const unsigned short*)(smem + G_OFF + G_BUF);
#pragma unroll
    for (int nt = 0; nt < 16; ++nt) {
      int g = lg ^ (nt & 3);
      int n = nt * 16 + l15;
      f16x8 bf = *(const f16x8*)(G + n * 32 + g * 8);
      accY[nt] = __builtin_amdgcn_mfma_f32_16x16x32_f16(cfC, bf, accY[nt], 0, 0, 0);
    }
  }

  // ---- epilogue ----
  {
    f32x4 bo;
#pragma unroll
    for (int r = 0; r < 4; ++r) bo[r] = b_out[wave * 16 + lg * 4 + r];
#pragma unroll
    for (int nt = 0; nt < 16; ++nt)
#pragma unroll
      for (int r = 0; r < 4; ++r) accY[nt][r] += bo[r];
  }

  if (t == 0) s_flag = 1;
  __syncthreads();
  {
    int ok = 1;
    const float* kc = ws;
#pragma unroll
    for (int j = 0; j < 16; ++j) {
      int idx = t * 16 + j;
      float e = ((idx & 63) == 0) ? 1.f : 0.f;
      ok &= (fabsf(kc[idx] - e) <= 1e-5f) ? 1 : 0;
    }
    if (!ok) s_flag = 0;
  }
  __syncthreads();

  const int o = wave * 16 + lg * 4;
  if (s_flag) {  // identity spectral filter: direct store
#pragma unroll
    for (int nt = 0; nt < 16; ++nt) {
      float* op = out + (((size_t)(b * 64 + o)) * IH + gy0 + nt) * IW + gx0 + l15;
#pragma unroll
      for (int r = 0; r < 4; ++r) op[(size_t)r * IH * IW] = accY[nt][r];
    }
    return;
  }

  // general path: per-patch circular convolution with kc (correct for any filter)
  float* YS = (float*)smem;  // [32][260]
  for (int half = 0; half < 2; ++half) {
    __syncthreads();
    if ((wave >> 1) == half) {
      int c32 = (wave & 1) * 16 + lg * 4;
#pragma unroll
      for (int nt = 0; nt < 16; ++nt)
#pragma unroll
        for (int r = 0; r < 4; ++r) YS[(c32 + r) * 260 + nt * 16 + l15] = accY[nt][r];
    }
    __syncthreads();
    if (t < 128) {
      int o32 = t >> 2, oo = half * 32 + o32, qd = t & 3;
      const float* kp = ws + oo * 64;
      int py0 = (qd >> 1) * 8, px0 = (qd & 1) * 8;
      const float* row = YS + o32 * 260;
      for (int i = 0; i < 8; ++i)
        for (int j = 0; j < 8; ++j) {
          float acc = 0.f;
          for (int a_ = 0; a_ < 8; ++a_)
            for (int b_ = 0; b_ < 8; ++b_)
              acc += kp[a_ * 8 + b_] *
                     row[(py0 + ((i - a_) & 7)) * 16 + px0 + ((j - b_) & 7)];
          out[(((size_t)(b * 64 + oo)) * IH + gy0 + py0 + i) * IW + gx0 + px0 + j] = acc;
        }
    }
  }
}

extern "C" void kernel_launch(void* const* d_in, const int* in_sizes, int n_in,
                              void* d_out, int out_size, void* d_ws, size_t ws_size,
                              hipStream_t stream) {
  const float* x = (const float*)d_in[0];
  const float* w_in = (const float*)d_in[1];
  const float* b_in = (const float*)d_in[2];
  const float* w_dw = (const float*)d_in[3];
  const float* b_dw = (const float*)d_in[4];
  const float* w_out = (const float*)d_in[5];
  const float* b_out = (const float*)d_in[6];
  const float* fftf = (const float*)d_in[7];
  float* out = (float*)d_out;
  float* ws = (float*)d_ws;

  edffn_prep<<<160, 64, 0, stream>>>(fftf, w_in, w_out, ws);
  dim3 grid(IW / TILE, IH / TILE, 4);
  edffn_main<<<grid, 256, 0, stream>>>(x, b_in, w_dw, b_dw, b_out, ws, out);
}

// Round 15
// 140.913 us; speedup vs baseline: 1.8497x; 1.8497x over previous
//
#include <hip/hip_runtime.h>
#include <math.h>

typedef __attribute__((ext_vector_type(8))) short short8;
typedef __attribute__((ext_vector_type(4))) float f32x4;
typedef __attribute__((ext_vector_type(2))) float f32x2;
typedef _Float16 f16x8 __attribute__((ext_vector_type(8)));

#define TILE 16
#define IH 256
#define IW 256

// ws byte layout: [0,16384) kc f32[64][64]; [16384,81920) wsA frags ushort (bf16);
//                 [81920,114688) wsC frags ushort (f16)
#define WSA_OFF 16384
#define WSC_OFF 81920

// LDS layout (bytes):
//   H[2]: @0, each [16 ch][1456] (18 rows x 80B + pad); px = packed f16 (h1,h2)
//   G[2]: @46592, each [256 px][64B = 4 granules, XOR gi=(ch>>3)^((px>>4)&3)], f16
//   slow-path YS f32[32][260] (33280 B) overlays @0
#define H_STRIDE 1456
#define H_BUF 23296
#define G_OFF 46592
#define G_BUF 16384
#define SMEM_BYTES 79360

__device__ __forceinline__ unsigned short f2bf(float f) {
  unsigned int u = __builtin_bit_cast(unsigned int, f);
  u = (u + 0x7FFFu + ((u >> 16) & 1u)) >> 16;
  return (unsigned short)u;
}

__global__ void edffn_prep(const float* __restrict__ fftf,
                           const float* __restrict__ w_in,
                           const float* __restrict__ w_out,
                           float* __restrict__ ws) {
  int blk = blockIdx.x, t = threadIdx.x;
  if (blk < 64) {
    // kc = irfft2 of the (real, symmetric) full-spectrum multiplier
    int a = t >> 3, bb = t & 7;
    const float c0 = 0.70710678118654752f;
    const float ctab[8] = {1.f, c0, 0.f, -c0, -1.f, -c0, 0.f, c0};
    const float* F = fftf + blk * 40;  // [8][5]
    float acc = 0.f;
    for (int k1 = 0; k1 < 8; ++k1)
      for (int k2 = 0; k2 < 8; ++k2) {
        float f = (k2 <= 4) ? F[k1 * 5 + k2] : F[((8 - k1) & 7) * 5 + (8 - k2)];
        acc += f * ctab[(k1 * a + k2 * bb) & 7];
      }
    ws[blk * 64 + t] = acc * (1.f / 64.f);
  } else if (blk < 128) {
    // w_in A-fragments (bf16): [chunk q=0..15][s=0,1][ks=0,1][lane][8]
    int b2 = blk - 64;
    int q = b2 >> 2, s = (b2 >> 1) & 1, ks = b2 & 1;
    int row = (s ? 256 : 0) + q * 16 + (t & 15);
    unsigned short* dst =
        (unsigned short*)((unsigned char*)ws + WSA_OFF) + (((q * 2 + s) * 2 + ks) * 64 + t) * 8;
    for (int j = 0; j < 8; ++j) {
      int k = ks * 32 + (t >> 4) * 8 + j;
      dst[j] = f2bf(w_in[row * 64 + k]);
    }
  } else {
    // w_out A-fragments (f16): [pair p=0..7][mtile=0..3][lane][8]
    int b3 = blk - 128;
    int p = b3 >> 2, mt = b3 & 3;
    int row = mt * 16 + (t & 15);
    unsigned short* dst =
        (unsigned short*)((unsigned char*)ws + WSC_OFF) + ((p * 4 + mt) * 64 + t) * 8;
    for (int j = 0; j < 8; ++j) {
      int k = p * 32 + (t >> 4) * 8 + j;
      _Float16 hv = (_Float16)w_out[row * 256 + k];
      dst[j] = __builtin_bit_cast(unsigned short, hv);
    }
  }
}

__global__ __launch_bounds__(256, 2) void edffn_main(
    const float* __restrict__ x, const float* __restrict__ b_in,
    const float* __restrict__ w_dw, const float* __restrict__ b_dw,
    const float* __restrict__ b_out, const float* __restrict__ ws,
    float* __restrict__ out) {
  __shared__ __align__(16) unsigned char smem[SMEM_BYTES];
  __shared__ int s_flag;
  const int t = threadIdx.x;
  const int lane = t & 63, wave = t >> 6;
  const int l15 = lane & 15, lg = lane >> 4;
  const int gx0 = blockIdx.x * TILE, gy0 = blockIdx.y * TILE;
  const int b = blockIdx.z;
  const unsigned short* wsA = (const unsigned short*)((const unsigned char*)ws + WSA_OFF);
  const unsigned short* wsC = (const unsigned short*)((const unsigned char*)ws + WSC_OFF);

  // ---- stage-A B-fragments (x halo, bf16) held in registers across all chunks ----
  short8 xf[6][2];
  int haddr[6];
  unsigned vmask = 0, imask = 0;
  const float* xb = x + (size_t)b * 64 * 65536;
#pragma unroll
  for (int i = 0; i < 6; ++i) {
    int nt = wave + 4 * i;  // wave0: 0,4,..,20 ; waves1-3: last invalid
    int n = nt * 16 + l15;
    int hy = n / 18;
    int hx = n - hy * 18;
    int gy = gy0 + hy - 1, gx = gx0 + hx - 1;
    int vnt = (nt < 21) & (n < 324);
    int inb = vnt & (gy >= 0) & (gy < IH) & (gx >= 0) & (gx < IW);
    haddr[i] = hy * 80 + hx * 4;
    vmask |= (unsigned)vnt << i;
    imask |= (unsigned)inb << i;
    int gyc = min(max(gy, 0), IH - 1), gxc = min(max(gx, 0), IW - 1);
    const float* xp = xb + (size_t)gyc * IW + gxc;
#pragma unroll
    for (int ks = 0; ks < 2; ++ks) {
#pragma unroll
      for (int j = 0; j < 8; ++j) {
        int k = ks * 32 + lg * 8 + j;
        unsigned short bf = f2bf(xp[(size_t)k * 65536]);
        xf[i][ks][j] = (short)(inb ? bf : (unsigned short)0);
      }
    }
  }

  f32x4 accY[16];
#pragma unroll
  for (int i = 0; i < 16; ++i) accY[i] = (f32x4){0.f, 0.f, 0.f, 0.f};

  const int cp_dw = t & 15;  // channel-in-chunk (wave spans all 16)
  const int oy_dw = t >> 4;  // output row 0..15

  auto loadWD = [&](int qq, unsigned (&wd)[9], unsigned& bd) {
    const int cg1 = qq * 16 + cp_dw, cg2 = 256 + qq * 16 + cp_dw;
#pragma unroll
    for (int u = 0; u < 9; ++u) {
      float w1 = w_dw[cg1 * 9 + u], w2 = w_dw[cg2 * 9 + u];
      asm("v_cvt_pkrtz_f16_f32 %0, %1, %2" : "=v"(wd[u]) : "v"(w1), "v"(w2));
    }
    float b1 = b_dw[cg1], b2 = b_dw[cg2];
    asm("v_cvt_pkrtz_f16_f32 %0, %1, %2" : "=v"(bd) : "v"(b1), "v"(b2));
  };

  // stage A for chunk qq into H[qq&1]
  auto stageA = [&](int qq) {
    short8 af[2][2];
#pragma unroll
    for (int s = 0; s < 2; ++s)
#pragma unroll
      for (int ks = 0; ks < 2; ++ks)
        af[s][ks] = *(const short8*)(wsA + (((qq * 2 + s) * 2 + ks) * 64 + lane) * 8);
    float bin[2][4];
#pragma unroll
    for (int s = 0; s < 2; ++s)
#pragma unroll
      for (int r = 0; r < 4; ++r) bin[s][r] = b_in[(s ? 256 : 0) + qq * 16 + lg * 4 + r];
    unsigned char* Hb = smem + (qq & 1) * H_BUF;
#pragma unroll
    for (int i = 0; i < 6; ++i) {
      if (wave + 4 * i < 21) {  // wave-uniform
        f32x4 acc0 = {0.f, 0.f, 0.f, 0.f}, acc1 = {0.f, 0.f, 0.f, 0.f};
        acc0 = __builtin_amdgcn_mfma_f32_16x16x32_bf16(af[0][0], xf[i][0], acc0, 0, 0, 0);
        acc0 = __builtin_amdgcn_mfma_f32_16x16x32_bf16(af[0][1], xf[i][1], acc0, 0, 0, 0);
        acc1 = __builtin_amdgcn_mfma_f32_16x16x32_bf16(af[1][0], xf[i][0], acc1, 0, 0, 0);
        acc1 = __builtin_amdgcn_mfma_f32_16x16x32_bf16(af[1][1], xf[i][1], acc1, 0, 0, 0);
        if ((vmask >> i) & 1u) {  // per-lane mask on writes only (MFMA stays convergent)
          unsigned keep = (imask >> i) & 1u;
#pragma unroll
          for (int r = 0; r < 4; ++r) {
            float v0 = acc0[r] + bin[0][r];
            float v1 = acc1[r] + bin[1][r];
            unsigned pk;
            asm("v_cvt_pkrtz_f16_f32 %0, %1, %2" : "=v"(pk) : "v"(v0), "v"(v1));
            pk = keep ? pk : 0u;  // SAME pad: h=0 outside image
            *(unsigned*)(Hb + (lg * 4 + r) * H_STRIDE + haddr[i]) = pk;
          }
        }
      }
    }
  };

  // packed-f16 GELU constants
#define PKC(nm, val)                                            \
  unsigned nm;                                                  \
  {                                                             \
    float fv = (val);                                           \
    asm("v_cvt_pkrtz_f16_f32 %0, %1, %1" : "=v"(nm) : "v"(fv)); \
  }
  PKC(kSQ, 0.70710678f)
  PKC(kC216, 1.f / 216.f)
  PKC(kCm42, -1.f / 42.f)
  PKC(kC10, 0.1f)
  PKC(kCm3, -1.f / 3.f)
  PKC(kOne, 1.0f)
  PKC(kHalf, 0.5f)
  PKC(kErf, 1.12837917f)
#undef PKC

  // dwconv 3x3 + packed-f16 GELU for chunk qq: reads H[qq&1], writes G[(qq>>1)&1]
  auto dwconv = [&](int qq, const unsigned (&wd)[9], unsigned bd) {
    const int cp = cp_dw, oy = oy_dw;
    const unsigned char* Hb = smem + (qq & 1) * H_BUF;
    unsigned a[16];
#pragma unroll
    for (int j = 0; j < 16; ++j) a[j] = bd;
#pragma unroll
    for (int dy = 0; dy < 3; ++dy) {
      const uint4* rp = (const uint4*)(Hb + cp * H_STRIDE + (oy + dy) * 80);
      uint4 r0 = rp[0], r1 = rp[1], r2 = rp[2], r3 = rp[3];
      uint2 r4 = ((const uint2*)rp)[8];
      unsigned e[18] = {r0.x, r0.y, r0.z, r0.w, r1.x, r1.y, r1.z, r1.w,
                        r2.x, r2.y, r2.z, r2.w, r3.x, r3.y, r3.z, r3.w,
                        r4.x, r4.y};
#pragma unroll
      for (int ox = 0; ox < 16; ++ox) {
#pragma unroll
        for (int dx = 0; dx < 3; ++dx)
          asm("v_pk_fma_f16 %0, %1, %2, %0"
              : "+v"(a[ox])
              : "v"(wd[dy * 3 + dx]), "v"(e[ox + dx]));
      }
    }
    const int c2 = (qq & 1) * 16 + cp;
    const int gi = (c2 >> 3) ^ (oy & 3);  // 16B-granule XOR swizzle (involution)
    unsigned short* Gp = (unsigned short*)(smem + G_OFF + ((qq >> 1) & 1) * G_BUF) +
                         oy * 16 * 32 + gi * 8 + (c2 & 7);
    unsigned umax = 0;
    unsigned gw[8];
#pragma unroll
    for (int j = 0; j < 8; ++j) {
      unsigned a0 = a[2 * j], a1 = a[2 * j + 1];
      unsigned u = __builtin_amdgcn_perm(a1, a0, 0x05040100u);
      unsigned v = __builtin_amdgcn_perm(a1, a0, 0x07060302u);
      unsigned uabs = u & 0x7FFF7FFFu;
      asm("v_pk_max_f16 %0, %1, %2" : "=v"(umax) : "v"(umax), "v"(uabs));
      unsigned z, z2, p, erfv, tt, g;
      asm("v_pk_mul_f16 %0, %1, %2" : "=v"(z) : "v"(u), "v"(kSQ));
      asm("v_pk_mul_f16 %0, %1, %2" : "=v"(z2) : "v"(z), "v"(z));
      asm("v_pk_fma_f16 %0, %1, %2, %3" : "=v"(p) : "v"(z2), "v"(kC216), "v"(kCm42));
      asm("v_pk_fma_f16 %0, %1, %2, %3" : "=v"(p) : "v"(z2), "v"(p), "v"(kC10));
      asm("v_pk_fma_f16 %0, %1, %2, %3" : "=v"(p) : "v"(z2), "v"(p), "v"(kCm3));
      asm("v_pk_fma_f16 %0, %1, %2, %3" : "=v"(p) : "v"(z2), "v"(p), "v"(kOne));
      asm("v_pk_mul_f16 %0, %1, %2" : "=v"(erfv) : "v"(z), "v"(p));
      asm("v_pk_mul_f16 %0, %1, %2" : "=v"(erfv) : "v"(erfv), "v"(kErf));
      asm("v_pk_fma_f16 %0, %1, %2, %2" : "=v"(tt) : "v"(erfv), "v"(kHalf));
      asm("v_pk_mul_f16 %0, %1, %2" : "=v"(g) : "v"(u), "v"(tt));
      asm("v_pk_mul_f16 %0, %1, %2" : "=v"(g) : "v"(g), "v"(v));
      gw[j] = g;
    }
    {  // exact fallback if any |z|>0.4 (cold; preserves correctness for any data)
      float m0, m1;
      unsigned uh = umax >> 16;
      asm("v_cvt_f32_f16 %0, %1" : "=v"(m0) : "v"(umax));
      asm("v_cvt_f32_f16 %0, %1" : "=v"(m1) : "v"(uh));
      if (__builtin_expect(fmaxf(m0, m1) > 0.565685f, 0)) {
#pragma unroll
        for (int j = 0; j < 8; ++j) {
          float g01[2];
#pragma unroll
          for (int kx = 0; kx < 2; ++kx) {
            unsigned aw = a[2 * j + kx], ah = aw >> 16;
            float hu, hv2;
            asm("v_cvt_f32_f16 %0, %1" : "=v"(hu) : "v"(aw));
            asm("v_cvt_f32_f16 %0, %1" : "=v"(hv2) : "v"(ah));
            g01[kx] = 0.5f * hu * (1.f + erff(hu * 0.70710678f)) * hv2;
          }
          unsigned pk;
          asm("v_cvt_pkrtz_f16_f32 %0, %1, %2" : "=v"(pk) : "v"(g01[0]), "v"(g01[1]));
          gw[j] = pk;
        }
      }
    }
#pragma unroll
    for (int j = 0; j < 8; ++j) {
      Gp[(2 * j) * 32] = (unsigned short)gw[j];
      Gp[(2 * j + 1) * 32] = (unsigned short)(gw[j] >> 16);
    }
  };

  unsigned wdA[9], wdB[9], bdA, bdB;
  f16x8 cfC;

  // 8 stage-C MFMAs for pair pc, rows nt0..nt0+7, from G[pc&1]
  auto stageC8 = [&](int pc, int nt0) {
    const unsigned short* G = (const unsigned short*)(smem + G_OFF + (pc & 1) * G_BUF);
#pragma unroll
    for (int k = 0; k < 8; ++k) {
      int nt = nt0 + k;
      int g = lg ^ (nt & 3);  // reader-side XOR (nt uniform per instr)
      int n = nt * 16 + l15;
      f16x8 bf = *(const f16x8*)(G + n * 32 + g * 8);
      accY[nt] = __builtin_amdgcn_mfma_f32_16x16x32_f16(cfC, bf, accY[nt], 0, 0, 0);
    }
  };

  // ---- prologue: weights + H(0),H(1) ----
  loadWD(0, wdA, bdA);
  loadWD(1, wdB, bdB);
  cfC = *(const f16x8*)(wsC + ((0 * 4 + wave) * 64 + lane) * 8);
  __builtin_amdgcn_s_setprio(1);
  stageA(0);
  stageA(1);
  __builtin_amdgcn_s_setprio(0);
  __syncthreads();

  for (int p = 0; p < 8; ++p) {
    // ---- D-phase: C(pair p-1) split around dwconv(2p), dwconv(2p+1) ----
    if (p >= 1) {
      __builtin_amdgcn_s_setprio(1);
      stageC8(p - 1, 0);
      __builtin_amdgcn_s_setprio(0);
    }
    dwconv(2 * p, wdA, bdA);
    if (p >= 1) {
      __builtin_amdgcn_s_setprio(1);
      stageC8(p - 1, 8);
      __builtin_amdgcn_s_setprio(0);
      cfC = *(const f16x8*)(wsC + ((p * 4 + wave) * 64 + lane) * 8);
    }
    dwconv(2 * p + 1, wdB, bdB);
    __syncthreads();

    // ---- A-phase: stage A for the next chunk pair ----
    if (p < 7) {
      __builtin_amdgcn_s_setprio(1);
      stageA(2 * p + 2);
      stageA(2 * p + 3);
      __builtin_amdgcn_s_setprio(0);
      loadWD(2 * p + 2, wdA, bdA);
      loadWD(2 * p + 3, wdB, bdB);
      __syncthreads();
    }
  }

  // ---- final stage C: pair 7 from G[1] ----
  __builtin_amdgcn_s_setprio(1);
  stageC8(7, 0);
  stageC8(7, 8);
  __builtin_amdgcn_s_setprio(0);

  // ---- epilogue ----
  {
    f32x4 bo;
#pragma unroll
    for (int r = 0; r < 4; ++r) bo[r] = b_out[wave * 16 + lg * 4 + r];
#pragma unroll
    for (int nt = 0; nt < 16; ++nt)
#pragma unroll
      for (int r = 0; r < 4; ++r) accY[nt][r] += bo[r];
  }

  if (t == 0) s_flag = 1;
  __syncthreads();
  {
    int ok = 1;
    const float* kc = ws;
#pragma unroll
    for (int j = 0; j < 16; ++j) {
      int idx = t * 16 + j;
      float e = ((idx & 63) == 0) ? 1.f : 0.f;
      ok &= (fabsf(kc[idx] - e) <= 1e-5f) ? 1 : 0;
    }
    if (!ok) s_flag = 0;
  }
  __syncthreads();

  const int o = wave * 16 + lg * 4;
  if (s_flag) {  // identity spectral filter: direct store
#pragma unroll
    for (int nt = 0; nt < 16; ++nt) {
      float* op = out + (((size_t)(b * 64 + o)) * IH + gy0 + nt) * IW + gx0 + l15;
#pragma unroll
      for (int r = 0; r < 4; ++r) op[(size_t)r * IH * IW] = accY[nt][r];
    }
    return;
  }

  // general path: per-patch circular convolution with kc (correct for any filter)
  float* YS = (float*)smem;  // [32][260]
  for (int half = 0; half < 2; ++half) {
    __syncthreads();
    if ((wave >> 1) == half) {
      int c32 = (wave & 1) * 16 + lg * 4;
#pragma unroll
      for (int nt = 0; nt < 16; ++nt)
#pragma unroll
        for (int r = 0; r < 4; ++r) YS[(c32 + r) * 260 + nt * 16 + l15] = accY[nt][r];
    }
    __syncthreads();
    if (t < 128) {
      int o32 = t >> 2, oo = half * 32 + o32, qd = t & 3;
      const float* kp = ws + oo * 64;
      int py0 = (qd >> 1) * 8, px0 = (qd & 1) * 8;
      const float* row = YS + o32 * 260;
      for (int i = 0; i < 8; ++i)
        for (int j = 0; j < 8; ++j) {
          float acc = 0.f;
          for (int a_ = 0; a_ < 8; ++a_)
            for (int b_ = 0; b_ < 8; ++b_)
              acc += kp[a_ * 8 + b_] *
                     row[(py0 + ((i - a_) & 7)) * 16 + px0 + ((j - b_) & 7)];
          out[(((size_t)(b * 64 + oo)) * IH + gy0 + py0 + i) * IW + gx0 + px0 + j] = acc;
        }
    }
  }
}

extern "C" void kernel_launch(void* const* d_in, const int* in_sizes, int n_in,
                              void* d_out, int out_size, void* d_ws, size_t ws_size,
                              hipStream_t stream) {
  const float* x = (const float*)d_in[0];
  const float* w_in = (const float*)d_in[1];
  const float* b_in = (const float*)d_in[2];
  const float* w_dw = (const float*)d_in[3];
  const float* b_dw = (const float*)d_in[4];
  const float* w_out = (const float*)d_in[5];
  const float* b_out = (const float*)d_in[6];
  const float* fftf = (const float*)d_in[7];
  float* out = (float*)d_out;
  float* ws = (float*)d_ws;

  edffn_prep<<<160, 64, 0, stream>>>(fftf, w_in, w_out, ws);
  dim3 grid(IW / TILE, IH / TILE, 4);
  edffn_main<<<grid, 256, 0, stream>>>(x, b_in, w_dw, b_dw, b_out, ws, out);
}